// Round 4
// baseline (729.343 us; speedup 1.0000x reference)
//
#include <hip/hip_runtime.h>
#include <hip/hip_bf16.h>
#include <stdint.h>

// ============================================================================
// MinGRU (2 layers), B=8 S=4096 D=H=1024.
//   1. x (f32) -> bf16
//   2. GEMM0: gh = x_bf16 @ W0^T + b0  -> bf16 gh   (M=32768,N=2048,K=1024)
//   3. scan0: chunked linear scan -> h1 (bf16)
//   4. GEMM1: gh = h1 @ W1^T + b1 -> bf16 gh
//   5. scan1: -> out (f32)
// R8: R7 + two MFMA-pipe fixes (sync structure unchanged from R7 = verified):
//   (a) k-outer MFMA order inside each quadrant: for ks { for f { for n }}.
//       R7 emitted acc=mfma(k0); acc=mfma(k1) back-to-back on the SAME acc
//       (dependent distance 1) -> in-order wave stalls at MFMA latency for
//       every 2nd instruction. Now dependent distance = 8 (~155 cyc).
//   (b) separate A register banks (Ar0 for mh=0, Ar1 for mh=1); A1's 8
//       ds_reads issue at PH0 tail (after MFMA_Q(0,0) issue, while the MFMA
//       pipe drains), drained by PH1's lgkm(0). Pre-MFMA read-waits go
//       12/4/8/0 -> 12/~4/0/0 per tile.
//   Hazard ledger (unchanged guarantees): A1 reads complete by PH1-lgkm(0),
//   all waves past barPH2 => complete; STG_A(1,T+2) still issues at ENDBLK
//   (after barPH3). vmcnt ledger identical to R7 (6 in flight at each
//   checkpoint = {B0,A0,A1}(T+2)).
// ============================================================================

typedef __attribute__((ext_vector_type(8))) short bf16x8;   // 8 bf16 = 4 VGPRs
typedef __attribute__((ext_vector_type(4))) float f32x4;

__device__ __forceinline__ unsigned short f2bf(float f) {
    union { float f; unsigned int u; } x; x.f = f;
    unsigned int r = x.u + 0x7fffu + ((x.u >> 16) & 1u);   // RNE
    return (unsigned short)(r >> 16);
}
__device__ __forceinline__ float bf2f(unsigned short u) {
    union { unsigned int i; float f; } x; x.i = ((unsigned int)u) << 16;
    return x.f;
}
// sigmoid with HW rcp (~2.4e-7 rel err; output rounds to bf16 anyway)
__device__ __forceinline__ float fsig(float x) {
    return __builtin_amdgcn_rcpf(1.0f + __expf(-x));
}

// async 16B/lane global->LDS. lds base wave-uniform; HW dest = lds + lane*16.
__device__ __forceinline__ void async_cp16(const void* g, void* lds) {
    __builtin_amdgcn_global_load_lds(
        (const __attribute__((address_space(1))) unsigned int*)g,
        (__attribute__((address_space(3))) unsigned int*)lds, 16, 0, 0);
}

// ---------------------------------------------------------------------------
__global__ void f32_to_bf16_k(const float* __restrict__ in,
                              unsigned short* __restrict__ out, int n8) {
    int i = blockIdx.x * blockDim.x + threadIdx.x;
    if (i >= n8) return;
    const float4* p = reinterpret_cast<const float4*>(in);
    float4 a = p[2 * i], b = p[2 * i + 1];
    float f[8] = {a.x, a.y, a.z, a.w, b.x, b.y, b.z, b.w};
    union { unsigned short s[8]; uint4 v; } u;
#pragma unroll
    for (int j = 0; j < 8; ++j) u.s[j] = f2bf(f[j]);
    *reinterpret_cast<uint4*>(out + (size_t)i * 8) = u.v;
}

// ---------------------------------------------------------------------------
// 256x256 8-phase GEMM: C[m,n] = sum_k A[m,k]*Wt[n,k] + bias[n], C bf16.
// Grid 1024 = 128 m-tiles x 8 n-tiles, XCD-swizzled (m-chunked per XCD).
// ---------------------------------------------------------------------------
__global__ __launch_bounds__(512, 2) void gemm256(
    const short* __restrict__ A, const short* __restrict__ Wt,
    const float* __restrict__ bias, unsigned short* __restrict__ C,
    int M, int N, int K)
{
    __shared__ __align__(16) short lds_a[32768];   // 2 bufs x 256 rows x 64 bf16
    __shared__ __align__(16) short lds_b[32768];

    const int tid  = threadIdx.x;
    const int lane = tid & 63;
    const int wave = tid >> 6;            // 0..7
    const int wm   = wave >> 2;           // 0..1 (rows wm*128..+127)
    const int wn   = wave & 3;            // 0..3 (cols wn*64..+63)

    // XCD swizzle: xcd = bid%8 (hw round-robin); each XCD covers a 16-m-tile
    // chunk for all 8 n-tiles -> A window shared in that XCD's L2.
    const int bid  = blockIdx.x;          // 0..1023
    const int slot = bid >> 3;            // 0..127
    const int mt   = (bid & 7) * 16 + (slot >> 3);  // 0..127
    const int nt   = slot & 7;                      // 0..7
    const int m0   = mt * 256, n0 = nt * 256;

    // per-lane LDS read offsets (shorts).  frag read: lane l -> row = r15
    // (within 16-row frag), k-chunk g = l>>4; swizzle chunk ^= row&7.
    const int g    = lane >> 4;
    const int x7   = lane & 7;
    const int r15  = lane & 15;
    const int aoff0 = (wm*128 + r15)*64 + (( g      ^ x7) * 8);
    const int aoff1 = (wm*128 + r15)*64 + (((4 + g) ^ x7) * 8);
    const int boff0 = (wn*64  + r15)*64 + (( g      ^ x7) * 8);
    const int boff1 = (wn*64  + r15)*64 + (((4 + g) ^ x7) * 8);

    // staging: thread -> row = half*128 + wave*16 + j*8 + (lane>>3),
    // physical chunk = lane&7, logical (global) chunk = (lane&7)^(lane>>3)
    // (inverse swizzle applied on the global source; LDS dest stays linear).
    const int srow = wave*16 + (lane >> 3);
    const int lch  = (lane & 7) ^ (lane >> 3);
    const short* pAs = A  + (size_t)(m0 + srow) * K + lch*8;
    const short* pBs = Wt + (size_t)(n0 + srow) * K + lch*8;
    const int dst = wave * 1024;          // shorts; +512 for j=1; lane*16B by HW

    f32x4  acc[8][4] = {};
    bf16x8 Ar0[4][2];       // mh=0 bank: 4 M-frags x 2 ksteps
    bf16x8 Ar1[4][2];       // mh=1 bank
    bf16x8 Br[2][2][2];     // [nh][n][kstep] (both nh halves live)

#define STG_A(h, kt) do { \
    async_cp16(pAs + (size_t)((h)*128    )*K + (kt)*64, lds_a + ((((kt)&1)*16384) + (h)*8192 + dst      )); \
    async_cp16(pAs + (size_t)((h)*128 + 8)*K + (kt)*64, lds_a + ((((kt)&1)*16384) + (h)*8192 + dst + 512)); } while (0)
#define STG_B(h, kt) do { \
    async_cp16(pBs + (size_t)((h)*128    )*K + (kt)*64, lds_b + ((((kt)&1)*16384) + (h)*8192 + dst      )); \
    async_cp16(pBs + (size_t)((h)*128 + 8)*K + (kt)*64, lds_b + ((((kt)&1)*16384) + (h)*8192 + dst + 512)); } while (0)

#define READ_A0(buf) do { _Pragma("unroll") \
    for (int f = 0; f < 4; ++f) { \
        Ar0[f][0] = *reinterpret_cast<const bf16x8*>(lds_a + (buf)*16384 + f*1024 + aoff0); \
        Ar0[f][1] = *reinterpret_cast<const bf16x8*>(lds_a + (buf)*16384 + f*1024 + aoff1); } } while (0)
#define READ_A1(buf) do { _Pragma("unroll") \
    for (int f = 0; f < 4; ++f) { \
        Ar1[f][0] = *reinterpret_cast<const bf16x8*>(lds_a + (buf)*16384 + 4096 + f*1024 + aoff0); \
        Ar1[f][1] = *reinterpret_cast<const bf16x8*>(lds_a + (buf)*16384 + 4096 + f*1024 + aoff1); } } while (0)
#define READ_B(nh, buf) do { _Pragma("unroll") \
    for (int n = 0; n < 2; ++n) { \
        Br[nh][n][0] = *reinterpret_cast<const bf16x8*>(lds_b + (buf)*16384 + (nh)*2048 + n*1024 + boff0); \
        Br[nh][n][1] = *reinterpret_cast<const bf16x8*>(lds_b + (buf)*16384 + (nh)*2048 + n*1024 + boff1); } } while (0)

// k-outer: dependent accumulations on the same acc are 8 MFMAs apart.
#define MFMA_Q(AR, mh, nh) do { \
    __builtin_amdgcn_s_setprio(1); \
    _Pragma("unroll") for (int ks = 0; ks < 2; ++ks) \
    _Pragma("unroll") for (int f = 0; f < 4; ++f) \
    _Pragma("unroll") for (int n = 0; n < 2; ++n) \
        acc[(mh)*4+f][(nh)*2+n] = __builtin_amdgcn_mfma_f32_16x16x32_bf16( \
            AR[f][ks], Br[nh][n][ks], acc[(mh)*4+f][(nh)*2+n], 0, 0, 0); \
    __builtin_amdgcn_s_setprio(0); } while (0)

#define SB() __builtin_amdgcn_sched_barrier(0)
#define NOP ((void)0)
// one barrier per phase: [stage; reads] | barrier | lgkm(0) | MFMA
// PH0 tail-issues READ_A1 while the MFMA pipe drains; PH1's lgkm(0) covers it.
#define PH0(b, STG) do { STG; READ_A0(b); READ_B(0,b); SB(); \
    __builtin_amdgcn_s_barrier(); \
    asm volatile("s_waitcnt lgkmcnt(0)" ::: "memory"); SB(); \
    MFMA_Q(Ar0,0,0); SB(); READ_A1(b); } while (0)
#define PH1(b) do { READ_B(1,b); SB(); \
    __builtin_amdgcn_s_barrier(); \
    asm volatile("s_waitcnt lgkmcnt(0)" ::: "memory"); SB(); MFMA_Q(Ar0,0,1); } while (0)
#define PH2(b) do { SB(); \
    __builtin_amdgcn_s_barrier(); \
    asm volatile("s_waitcnt lgkmcnt(0)" ::: "memory"); SB(); MFMA_Q(Ar1,1,0); } while (0)
#define PH3(b, STG) do { STG; SB(); \
    __builtin_amdgcn_s_barrier(); \
    asm volatile("s_waitcnt lgkmcnt(0)" ::: "memory"); SB(); MFMA_Q(Ar1,1,1); } while (0)
// ENDBLK zone sits after bar3: A-half stages of tile T+2 are safe here.
#define ENDBLK(n, S1, S2) do { S1; S2; SB(); \
    asm volatile("s_waitcnt vmcnt(" #n ")" ::: "memory"); \
    __builtin_amdgcn_s_barrier(); SB(); } while (0)

    // prologue: tile0 fully + tile1's {B0,A0,A1}; vmcnt(6) -> tile0 resident,
    // exactly the carryover set {B0,A0,A1}(1) (6 loads) left in flight.
    STG_A(0, 0); STG_A(1, 0); STG_B(0, 0); STG_B(1, 0);
    STG_B(0, 1); STG_A(0, 1); STG_A(1, 1);
    ENDBLK(6, NOP, NOP);

#pragma unroll 1
    for (int i = 0; i < 7; ++i) {
        const int kt = 2 * i;
        // block T = kt (buf0)
        PH0(0, STG_B(1, kt + 1));
        PH1(0);
        PH2(0);
        PH3(0, STG_B(0, kt + 2));
        ENDBLK(6, STG_A(0, kt + 2), STG_A(1, kt + 2));
        // block T = kt+1 (buf1)
        PH0(1, STG_B(1, kt + 2));
        PH1(1);
        PH2(1);
        PH3(1, STG_B(0, kt + 3));
        ENDBLK(6, STG_A(0, kt + 3), STG_A(1, kt + 3));
    }
    // T=14 (buf0): only B1(15) left to stage; drain fully before T=15.
    PH0(0, STG_B(1, 15));
    PH1(0);
    PH2(0);
    PH3(0, NOP);
    ENDBLK(0, NOP, NOP);
    // T=15 (buf1): no staging.
    PH0(1, NOP);
    PH1(1);
    PH2(1);
    PH3(1, NOP);

    // epilogue: C/D layout col=lane&15, row=quad*4+reg
    const int quad  = lane >> 4;
    const int ccol0 = n0 + wn*64 + r15;
    const size_t crow0 = (size_t)(m0 + wm*128 + quad*4);
    float bv[4];
#pragma unroll
    for (int n = 0; n < 4; ++n) bv[n] = bias[ccol0 + n*16];
#pragma unroll
    for (int f = 0; f < 8; ++f)
#pragma unroll
        for (int r = 0; r < 4; ++r) {
            const size_t row = crow0 + f*16 + r;
#pragma unroll
            for (int n = 0; n < 4; ++n)
                C[row * N + ccol0 + n*16] = f2bf(acc[f][n][r] + bv[n]);
        }
#undef STG_A
#undef STG_B
#undef READ_A0
#undef READ_A1
#undef READ_B
#undef MFMA_Q
#undef SB
#undef NOP
#undef PH0
#undef PH1
#undef PH2
#undef PH3
#undef ENDBLK
}

// ---------------------------------------------------------------------------
// Scans over bf16 gh:(B*S,2048); gate=[0,1024), hidden=[1024,2048).
// 128 chunks of 32 steps; 4 channels/thread. ch = b*1024+h.
// ---------------------------------------------------------------------------
__global__ void scan_partial(const unsigned short* __restrict__ gh,
                             float* __restrict__ P, float* __restrict__ V) {
    const int h4 = threadIdx.x;                 // 0..255 -> channels h4*4..+3
    const int j = blockIdx.y, b = blockIdx.z;
    const size_t base = ((size_t)b * 4096 + (size_t)j * 32) * 2048 + h4 * 4;
    float p[4] = {1, 1, 1, 1}, hl[4] = {0, 0, 0, 0};
#pragma unroll 8
    for (int t = 0; t < 32; ++t) {
        ushort4 g  = *reinterpret_cast<const ushort4*>(gh + base + (size_t)t * 2048);
        ushort4 hd = *reinterpret_cast<const ushort4*>(gh + base + (size_t)t * 2048 + 1024);
        const unsigned short ga[4] = {g.x, g.y, g.z, g.w};
        const unsigned short ha[4] = {hd.x, hd.y, hd.z, hd.w};
#pragma unroll
        for (int c = 0; c < 4; ++c) {
            float gf = bf2f(ga[c]), hf = bf2f(ha[c]);
            float z  = fsig(gf);
            float cc = 1.0f - z;
            float gv = (hf >= 0.0f) ? (hf + 0.5f) : fsig(hf);
            p[c]  = p[c] * cc;
            hl[c] = cc * hl[c] + z * gv;
        }
    }
    const int ch = b * 1024 + h4 * 4;
    *reinterpret_cast<float4*>(P + (size_t)j * 8192 + ch) = make_float4(p[0], p[1], p[2], p[3]);
    *reinterpret_cast<float4*>(V + (size_t)j * 8192 + ch) = make_float4(hl[0], hl[1], hl[2], hl[3]);
}

// 1 channel/thread: 8192 threads (32 blocks) vs old 2048 (8 blocks).
__global__ void scan_combine(const float* __restrict__ P,
                             const float* __restrict__ V,
                             float* __restrict__ hstart) {
    const int ch = blockIdx.x * blockDim.x + threadIdx.x;  // 0..8191
    float h = 0.5f;                                        // h0 = g(0) = 0.5
#pragma unroll 8
    for (int j = 0; j < 128; ++j) {
        hstart[(size_t)j * 8192 + ch] = h;
        h = P[(size_t)j * 8192 + ch] * h + V[(size_t)j * 8192 + ch];
    }
}

template <bool BF16OUT, typename OUT>
__global__ void scan_final(const unsigned short* __restrict__ gh,
                           const float* __restrict__ hstart,
                           OUT* __restrict__ out) {
    const int h4 = threadIdx.x;
    const int j = blockIdx.y, b = blockIdx.z;
    const size_t base  = ((size_t)b * 4096 + (size_t)j * 32) * 2048 + h4 * 4;
    const size_t obase = ((size_t)b * 4096 + (size_t)j * 32) * 1024 + h4 * 4;
    float4 hq = *reinterpret_cast<const float4*>(hstart + (size_t)j * 8192 + b * 1024 + h4 * 4);
    float hv[4] = {hq.x, hq.y, hq.z, hq.w};
#pragma unroll 8
    for (int t = 0; t < 32; ++t) {
        ushort4 g  = *reinterpret_cast<const ushort4*>(gh + base + (size_t)t * 2048);
        ushort4 hd = *reinterpret_cast<const ushort4*>(gh + base + (size_t)t * 2048 + 1024);
        const unsigned short ga[4] = {g.x, g.y, g.z, g.w};
        const unsigned short ha[4] = {hd.x, hd.y, hd.z, hd.w};
#pragma unroll
        for (int c = 0; c < 4; ++c) {
            float gf = bf2f(ga[c]), hf = bf2f(ha[c]);
            float z  = fsig(gf);
            float cc = 1.0f - z;
            float gv = (hf >= 0.0f) ? (hf + 0.5f) : fsig(hf);
            hv[c] = cc * hv[c] + z * gv;
        }
        if (BF16OUT) {
            ushort4 o = make_ushort4(f2bf(hv[0]), f2bf(hv[1]), f2bf(hv[2]), f2bf(hv[3]));
            *reinterpret_cast<ushort4*>((unsigned short*)out + obase + (size_t)t * 1024) = o;
        } else {
            *reinterpret_cast<float4*>((float*)out + obase + (size_t)t * 1024) =
                make_float4(hv[0], hv[1], hv[2], hv[3]);
        }
    }
}

// ---------------------------------------------------------------------------
extern "C" void kernel_launch(void* const* d_in, const int* in_sizes, int n_in,
                              void* d_out, int out_size, void* d_ws, size_t ws_size,
                              hipStream_t stream) {
    const float* x  = (const float*)d_in[0];   // (8,4096,1024)
    const float* W0 = (const float*)d_in[1];   // (2048,1024)
    const float* b0 = (const float*)d_in[2];   // (2048,)
    const float* W1 = (const float*)d_in[3];   // (2048,1024)
    const float* b1 = (const float*)d_in[4];   // (2048,)
    float* out = (float*)d_out;                // (8,4096,1024) f32

    char* ws = (char*)d_ws;
    unsigned short* gh   = (unsigned short*)ws;                      // 128MB bf16
    unsigned short* abuf = (unsigned short*)(ws + 0x08000000);       // 64MB x/h1 bf16
    unsigned short* w0b  = (unsigned short*)(ws + 0x0C000000);       // 4MB
    unsigned short* w1b  = (unsigned short*)(ws + 0x0C400000);       // 4MB
    float*          P    = (float*)(ws + 0x0C800000);                // 4MB
    float*          V    = (float*)(ws + 0x0CC00000);                // 4MB
    float*          hst  = (float*)(ws + 0x0D000000);                // 4MB

    const int M = 32768, N = 2048, K = 1024;

    f32_to_bf16_k<<<4194304 / 256, 256, 0, stream>>>(x,  abuf, 4194304);
    f32_to_bf16_k<<<262144 / 256, 256, 0, stream>>>(W0, w0b, 262144);
    f32_to_bf16_k<<<262144 / 256, 256, 0, stream>>>(W1, w1b, 262144);

    dim3 sg(1, 128, 8);          // (-, chunks, batch), 256 thr = 1024 ch / 4

    // layer 0
    gemm256<<<1024, 512, 0, stream>>>((const short*)abuf, (const short*)w0b, b0, gh, M, N, K);
    scan_partial<<<sg, 256, 0, stream>>>(gh, P, V);
    scan_combine<<<32, 256, 0, stream>>>(P, V, hst);
    scan_final<true, unsigned short><<<sg, 256, 0, stream>>>(gh, hst, abuf);  // h1 bf16

    // layer 1
    gemm256<<<1024, 512, 0, stream>>>((const short*)abuf, (const short*)w1b, b1, gh, M, N, K);
    scan_partial<<<sg, 256, 0, stream>>>(gh, P, V);
    scan_combine<<<32, 256, 0, stream>>>(P, V, hst);
    scan_final<false, float><<<sg, 256, 0, stream>>>(gh, hst, out);
}

// Round 5
// 620.593 us; speedup vs baseline: 1.1752x; 1.1752x over previous
//
#include <hip/hip_runtime.h>
#include <hip/hip_bf16.h>
#include <stdint.h>

// ============================================================================
// MinGRU (2 layers), B=8 S=4096 D=H=1024.
//   1. x (f32) -> bf16
//   2. GEMM0: gh = x_bf16 @ W0^T + b0  -> bf16 gh   (M=32768,N=2048,K=1024)
//   3. scan0: chunked linear scan -> h1 (bf16)
//   4. GEMM1: gh = h1 @ W1^T + b1 -> bf16 gh
//   5. scan1: -> out (f32)
// R9: R7 skeleton (verified ledger) + ONE change: fragment LDS reads are now
//     volatile inline-asm ds_read_b128 (addr VGPR + compile-time offset:).
//     Rationale: IR-visible ds_reads let the backend waitcnt pass order them
//     against outstanding global_load_lds DMA (conservative aliasing) ->
//     a ~900cy vmcnt drain per phase, which explains R5==R7==150us and the
//     5625 cy/K-tile vs 2060 cy MFMA floor. Asm reads are invisible to the
//     pass; correctness now rests ONLY on R7's verified barrier+vmcnt(6)
//     ledger (volatile asm is order-preserved vs the volatile barriers and
//     side-effecting DMA intrinsics; read->MFMA covered by lgkmcnt(0)+SB,
//     rule 18). R8's spilling A-bank reverted (WRITE_SIZE +30MB = scratch).
// ============================================================================

typedef __attribute__((ext_vector_type(8))) short bf16x8;   // 8 bf16 = 4 VGPRs
typedef __attribute__((ext_vector_type(4))) float f32x4;

__device__ __forceinline__ unsigned short f2bf(float f) {
    union { float f; unsigned int u; } x; x.f = f;
    unsigned int r = x.u + 0x7fffu + ((x.u >> 16) & 1u);   // RNE
    return (unsigned short)(r >> 16);
}
__device__ __forceinline__ float bf2f(unsigned short u) {
    union { unsigned int i; float f; } x; x.i = ((unsigned int)u) << 16;
    return x.f;
}
// sigmoid with HW rcp (~2.4e-7 rel err; output rounds to bf16 anyway)
__device__ __forceinline__ float fsig(float x) {
    return __builtin_amdgcn_rcpf(1.0f + __expf(-x));
}

// async 16B/lane global->LDS. lds base wave-uniform; HW dest = lds + lane*16.
__device__ __forceinline__ void async_cp16(const void* g, void* lds) {
    __builtin_amdgcn_global_load_lds(
        (const __attribute__((address_space(1))) unsigned int*)g,
        (__attribute__((address_space(3))) unsigned int*)lds, 16, 0, 0);
}

// ---------------------------------------------------------------------------
__global__ void f32_to_bf16_k(const float* __restrict__ in,
                              unsigned short* __restrict__ out, int n8) {
    int i = blockIdx.x * blockDim.x + threadIdx.x;
    if (i >= n8) return;
    const float4* p = reinterpret_cast<const float4*>(in);
    float4 a = p[2 * i], b = p[2 * i + 1];
    float f[8] = {a.x, a.y, a.z, a.w, b.x, b.y, b.z, b.w};
    union { unsigned short s[8]; uint4 v; } u;
#pragma unroll
    for (int j = 0; j < 8; ++j) u.s[j] = f2bf(f[j]);
    *reinterpret_cast<uint4*>(out + (size_t)i * 8) = u.v;
}

// ---------------------------------------------------------------------------
// 256x256 8-phase GEMM: C[m,n] = sum_k A[m,k]*Wt[n,k] + bias[n], C bf16.
// Grid 1024 = 128 m-tiles x 8 n-tiles, XCD-swizzled (m-chunked per XCD).
// ---------------------------------------------------------------------------
__global__ __launch_bounds__(512, 2) void gemm256(
    const short* __restrict__ A, const short* __restrict__ Wt,
    const float* __restrict__ bias, unsigned short* __restrict__ C,
    int M, int N, int K)
{
    __shared__ __align__(16) short lds_a[32768];   // 2 bufs x 256 rows x 64 bf16
    __shared__ __align__(16) short lds_b[32768];

    const int tid  = threadIdx.x;
    const int lane = tid & 63;
    const int wave = tid >> 6;            // 0..7
    const int wm   = wave >> 2;           // 0..1 (rows wm*128..+127)
    const int wn   = wave & 3;            // 0..3 (cols wn*64..+63)

    // XCD swizzle: xcd = bid%8 (hw round-robin); each XCD covers a 16-m-tile
    // chunk for all 8 n-tiles -> A window shared in that XCD's L2.
    const int bid  = blockIdx.x;          // 0..1023
    const int slot = bid >> 3;            // 0..127
    const int mt   = (bid & 7) * 16 + (slot >> 3);  // 0..127
    const int nt   = slot & 7;                      // 0..7
    const int m0   = mt * 256, n0 = nt * 256;

    // per-lane LDS read offsets (shorts).  frag read: lane l -> row = r15
    // (within 16-row frag), k-chunk g = l>>4; swizzle chunk ^= row&7.
    const int g    = lane >> 4;
    const int x7   = lane & 7;
    const int r15  = lane & 15;
    const int aoff0 = (wm*128 + r15)*64 + (( g      ^ x7) * 8);
    const int aoff1 = (wm*128 + r15)*64 + (((4 + g) ^ x7) * 8);
    const int boff0 = (wn*64  + r15)*64 + (( g      ^ x7) * 8);
    const int boff1 = (wn*64  + r15)*64 + (((4 + g) ^ x7) * 8);

    // LDS byte addresses for the asm ds_reads (32-bit LDS pointers).
    const unsigned adr_a0 = (unsigned)(uintptr_t)&lds_a[aoff0];
    const unsigned adr_a1 = (unsigned)(uintptr_t)&lds_a[aoff1];
    const unsigned adr_b0 = (unsigned)(uintptr_t)&lds_b[boff0];
    const unsigned adr_b1 = (unsigned)(uintptr_t)&lds_b[boff1];

    // staging: thread -> row = half*128 + wave*16 + j*8 + (lane>>3),
    // physical chunk = lane&7, logical (global) chunk = (lane&7)^(lane>>3)
    // (inverse swizzle applied on the global source; LDS dest stays linear).
    const int srow = wave*16 + (lane >> 3);
    const int lch  = (lane & 7) ^ (lane >> 3);
    const short* pAs = A  + (size_t)(m0 + srow) * K + lch*8;
    const short* pBs = Wt + (size_t)(n0 + srow) * K + lch*8;
    const int dst = wave * 1024;          // shorts; +512 for j=1; lane*16B by HW

    f32x4  acc[8][4] = {};
    bf16x8 Ar[4][2];        // 4 M-frags x 2 ksteps (reused across mh)
    bf16x8 Br[2][2][2];     // [nh][n][kstep] (both nh halves live)

#define STG_A(h, kt) do { \
    async_cp16(pAs + (size_t)((h)*128    )*K + (kt)*64, lds_a + ((((kt)&1)*16384) + (h)*8192 + dst      )); \
    async_cp16(pAs + (size_t)((h)*128 + 8)*K + (kt)*64, lds_a + ((((kt)&1)*16384) + (h)*8192 + dst + 512)); } while (0)
#define STG_B(h, kt) do { \
    async_cp16(pBs + (size_t)((h)*128    )*K + (kt)*64, lds_b + ((((kt)&1)*16384) + (h)*8192 + dst      )); \
    async_cp16(pBs + (size_t)((h)*128 + 8)*K + (kt)*64, lds_b + ((((kt)&1)*16384) + (h)*8192 + dst + 512)); } while (0)

// volatile asm ds_read_b128: invisible to the waitcnt pass (no auto-vmcnt
// vs outstanding LDS-DMA); ordered vs barriers/waitcnts (all volatile asm)
// and vs the side-effecting global_load_lds intrinsics. offsets in BYTES:
// buf*32768 + mh*8192 + f*2048   (A);   buf*32768 + nh*4096 + n*2048  (B).
#define DSRD(dstv, base, imm) \
    asm volatile("ds_read_b128 %0, %1 offset:%c2" : "=v"(dstv) : "v"(base), "n"(imm))

#define READ_A(mh, buf) do { _Pragma("unroll") \
    for (int f = 0; f < 4; ++f) { \
        DSRD(Ar[f][0], adr_a0, (buf)*32768 + (mh)*8192 + f*2048); \
        DSRD(Ar[f][1], adr_a1, (buf)*32768 + (mh)*8192 + f*2048); } } while (0)
#define READ_B(nh, buf) do { _Pragma("unroll") \
    for (int n = 0; n < 2; ++n) { \
        DSRD(Br[nh][n][0], adr_b0, (buf)*32768 + (nh)*4096 + n*2048); \
        DSRD(Br[nh][n][1], adr_b1, (buf)*32768 + (nh)*4096 + n*2048); } } while (0)

// k-outer: dependent accumulations on the same acc are 8 MFMAs apart.
#define MFMA_Q(mh, nh) do { \
    __builtin_amdgcn_s_setprio(1); \
    _Pragma("unroll") for (int ks = 0; ks < 2; ++ks) \
    _Pragma("unroll") for (int f = 0; f < 4; ++f) \
    _Pragma("unroll") for (int n = 0; n < 2; ++n) \
        acc[(mh)*4+f][(nh)*2+n] = __builtin_amdgcn_mfma_f32_16x16x32_bf16( \
            Ar[f][ks], Br[nh][n][ks], acc[(mh)*4+f][(nh)*2+n], 0, 0, 0); \
    __builtin_amdgcn_s_setprio(0); } while (0)

#define SB() __builtin_amdgcn_sched_barrier(0)
#define NOP ((void)0)
// one barrier per phase: [stage; reads] | barrier | lgkm(0) | SB | MFMA
#define PH0(b, STG) do { STG; READ_A(0,b); READ_B(0,b); SB(); \
    __builtin_amdgcn_s_barrier(); \
    asm volatile("s_waitcnt lgkmcnt(0)" ::: "memory"); SB(); MFMA_Q(0,0); } while (0)
#define PH1(b) do { READ_B(1,b); SB(); \
    __builtin_amdgcn_s_barrier(); \
    asm volatile("s_waitcnt lgkmcnt(0)" ::: "memory"); SB(); MFMA_Q(0,1); } while (0)
#define PH2(b) do { READ_A(1,b); SB(); \
    __builtin_amdgcn_s_barrier(); \
    asm volatile("s_waitcnt lgkmcnt(0)" ::: "memory"); SB(); MFMA_Q(1,0); } while (0)
#define PH3(b, STG) do { STG; SB(); \
    __builtin_amdgcn_s_barrier(); \
    asm volatile("s_waitcnt lgkmcnt(0)" ::: "memory"); SB(); MFMA_Q(1,1); } while (0)
// ENDBLK zone sits after bar3: A-half stages of tile T+2 are safe here.
#define ENDBLK(n, S1, S2) do { S1; S2; SB(); \
    asm volatile("s_waitcnt vmcnt(" #n ")" ::: "memory"); \
    __builtin_amdgcn_s_barrier(); SB(); } while (0)

    // prologue: tile0 fully + tile1's {B0,A0,A1}; vmcnt(6) -> tile0 resident,
    // exactly the carryover set {B0,A0,A1}(1) (6 loads) left in flight.
    STG_A(0, 0); STG_A(1, 0); STG_B(0, 0); STG_B(1, 0);
    STG_B(0, 1); STG_A(0, 1); STG_A(1, 1);
    ENDBLK(6, NOP, NOP);

#pragma unroll 1
    for (int i = 0; i < 7; ++i) {
        const int kt = 2 * i;
        // block T = kt (buf0)
        PH0(0, STG_B(1, kt + 1));
        PH1(0);
        PH2(0);
        PH3(0, STG_B(0, kt + 2));
        ENDBLK(6, STG_A(0, kt + 2), STG_A(1, kt + 2));
        // block T = kt+1 (buf1)
        PH0(1, STG_B(1, kt + 2));
        PH1(1);
        PH2(1);
        PH3(1, STG_B(0, kt + 3));
        ENDBLK(6, STG_A(0, kt + 3), STG_A(1, kt + 3));
    }
    // T=14 (buf0): only B1(15) left to stage; drain fully before T=15.
    PH0(0, STG_B(1, 15));
    PH1(0);
    PH2(0);
    PH3(0, NOP);
    ENDBLK(0, NOP, NOP);
    // T=15 (buf1): no staging.
    PH0(1, NOP);
    PH1(1);
    PH2(1);
    PH3(1, NOP);

    // epilogue: C/D layout col=lane&15, row=quad*4+reg
    const int quad  = lane >> 4;
    const int ccol0 = n0 + wn*64 + r15;
    const size_t crow0 = (size_t)(m0 + wm*128 + quad*4);
    float bv[4];
#pragma unroll
    for (int n = 0; n < 4; ++n) bv[n] = bias[ccol0 + n*16];
#pragma unroll
    for (int f = 0; f < 8; ++f)
#pragma unroll
        for (int r = 0; r < 4; ++r) {
            const size_t row = crow0 + f*16 + r;
#pragma unroll
            for (int n = 0; n < 4; ++n)
                C[row * N + ccol0 + n*16] = f2bf(acc[f][n][r] + bv[n]);
        }
#undef STG_A
#undef STG_B
#undef DSRD
#undef READ_A
#undef READ_B
#undef MFMA_Q
#undef SB
#undef NOP
#undef PH0
#undef PH1
#undef PH2
#undef PH3
#undef ENDBLK
}

// ---------------------------------------------------------------------------
// Scans over bf16 gh:(B*S,2048); gate=[0,1024), hidden=[1024,2048).
// 128 chunks of 32 steps; 4 channels/thread. ch = b*1024+h.
// ---------------------------------------------------------------------------
__global__ void scan_partial(const unsigned short* __restrict__ gh,
                             float* __restrict__ P, float* __restrict__ V) {
    const int h4 = threadIdx.x;                 // 0..255 -> channels h4*4..+3
    const int j = blockIdx.y, b = blockIdx.z;
    const size_t base = ((size_t)b * 4096 + (size_t)j * 32) * 2048 + h4 * 4;
    float p[4] = {1, 1, 1, 1}, hl[4] = {0, 0, 0, 0};
#pragma unroll 8
    for (int t = 0; t < 32; ++t) {
        ushort4 g  = *reinterpret_cast<const ushort4*>(gh + base + (size_t)t * 2048);
        ushort4 hd = *reinterpret_cast<const ushort4*>(gh + base + (size_t)t * 2048 + 1024);
        const unsigned short ga[4] = {g.x, g.y, g.z, g.w};
        const unsigned short ha[4] = {hd.x, hd.y, hd.z, hd.w};
#pragma unroll
        for (int c = 0; c < 4; ++c) {
            float gf = bf2f(ga[c]), hf = bf2f(ha[c]);
            float z  = fsig(gf);
            float cc = 1.0f - z;
            float gv = (hf >= 0.0f) ? (hf + 0.5f) : fsig(hf);
            p[c]  = p[c] * cc;
            hl[c] = cc * hl[c] + z * gv;
        }
    }
    const int ch = b * 1024 + h4 * 4;
    *reinterpret_cast<float4*>(P + (size_t)j * 8192 + ch) = make_float4(p[0], p[1], p[2], p[3]);
    *reinterpret_cast<float4*>(V + (size_t)j * 8192 + ch) = make_float4(hl[0], hl[1], hl[2], hl[3]);
}

// 1 channel/thread: 8192 threads (32 blocks) vs old 2048 (8 blocks).
__global__ void scan_combine(const float* __restrict__ P,
                             const float* __restrict__ V,
                             float* __restrict__ hstart) {
    const int ch = blockIdx.x * blockDim.x + threadIdx.x;  // 0..8191
    float h = 0.5f;                                        // h0 = g(0) = 0.5
#pragma unroll 8
    for (int j = 0; j < 128; ++j) {
        hstart[(size_t)j * 8192 + ch] = h;
        h = P[(size_t)j * 8192 + ch] * h + V[(size_t)j * 8192 + ch];
    }
}

template <bool BF16OUT, typename OUT>
__global__ void scan_final(const unsigned short* __restrict__ gh,
                           const float* __restrict__ hstart,
                           OUT* __restrict__ out) {
    const int h4 = threadIdx.x;
    const int j = blockIdx.y, b = blockIdx.z;
    const size_t base  = ((size_t)b * 4096 + (size_t)j * 32) * 2048 + h4 * 4;
    const size_t obase = ((size_t)b * 4096 + (size_t)j * 32) * 1024 + h4 * 4;
    float4 hq = *reinterpret_cast<const float4*>(hstart + (size_t)j * 8192 + b * 1024 + h4 * 4);
    float hv[4] = {hq.x, hq.y, hq.z, hq.w};
#pragma unroll 8
    for (int t = 0; t < 32; ++t) {
        ushort4 g  = *reinterpret_cast<const ushort4*>(gh + base + (size_t)t * 2048);
        ushort4 hd = *reinterpret_cast<const ushort4*>(gh + base + (size_t)t * 2048 + 1024);
        const unsigned short ga[4] = {g.x, g.y, g.z, g.w};
        const unsigned short ha[4] = {hd.x, hd.y, hd.z, hd.w};
#pragma unroll
        for (int c = 0; c < 4; ++c) {
            float gf = bf2f(ga[c]), hf = bf2f(ha[c]);
            float z  = fsig(gf);
            float cc = 1.0f - z;
            float gv = (hf >= 0.0f) ? (hf + 0.5f) : fsig(hf);
            hv[c] = cc * hv[c] + z * gv;
        }
        if (BF16OUT) {
            ushort4 o = make_ushort4(f2bf(hv[0]), f2bf(hv[1]), f2bf(hv[2]), f2bf(hv[3]));
            *reinterpret_cast<ushort4*>((unsigned short*)out + obase + (size_t)t * 1024) = o;
        } else {
            *reinterpret_cast<float4*>((float*)out + obase + (size_t)t * 1024) =
                make_float4(hv[0], hv[1], hv[2], hv[3]);
        }
    }
}

// ---------------------------------------------------------------------------
extern "C" void kernel_launch(void* const* d_in, const int* in_sizes, int n_in,
                              void* d_out, int out_size, void* d_ws, size_t ws_size,
                              hipStream_t stream) {
    const float* x  = (const float*)d_in[0];   // (8,4096,1024)
    const float* W0 = (const float*)d_in[1];   // (2048,1024)
    const float* b0 = (const float*)d_in[2];   // (2048,)
    const float* W1 = (const float*)d_in[3];   // (2048,1024)
    const float* b1 = (const float*)d_in[4];   // (2048,)
    float* out = (float*)d_out;                // (8,4096,1024) f32

    char* ws = (char*)d_ws;
    unsigned short* gh   = (unsigned short*)ws;                      // 128MB bf16
    unsigned short* abuf = (unsigned short*)(ws + 0x08000000);       // 64MB x/h1 bf16
    unsigned short* w0b  = (unsigned short*)(ws + 0x0C000000);       // 4MB
    unsigned short* w1b  = (unsigned short*)(ws + 0x0C400000);       // 4MB
    float*          P    = (float*)(ws + 0x0C800000);                // 4MB
    float*          V    = (float*)(ws + 0x0CC00000);                // 4MB
    float*          hst  = (float*)(ws + 0x0D000000);                // 4MB

    const int M = 32768, N = 2048, K = 1024;

    f32_to_bf16_k<<<4194304 / 256, 256, 0, stream>>>(x,  abuf, 4194304);
    f32_to_bf16_k<<<262144 / 256, 256, 0, stream>>>(W0, w0b, 262144);
    f32_to_bf16_k<<<262144 / 256, 256, 0, stream>>>(W1, w1b, 262144);

    dim3 sg(1, 128, 8);          // (-, chunks, batch), 256 thr = 1024 ch / 4

    // layer 0
    gemm256<<<1024, 512, 0, stream>>>((const short*)abuf, (const short*)w0b, b0, gh, M, N, K);
    scan_partial<<<sg, 256, 0, stream>>>(gh, P, V);
    scan_combine<<<32, 256, 0, stream>>>(P, V, hst);
    scan_final<true, unsigned short><<<sg, 256, 0, stream>>>(gh, hst, abuf);  // h1 bf16

    // layer 1
    gemm256<<<1024, 512, 0, stream>>>((const short*)abuf, (const short*)w1b, b1, gh, M, N, K);
    scan_partial<<<sg, 256, 0, stream>>>(gh, P, V);
    scan_combine<<<32, 256, 0, stream>>>(P, V, hst);
    scan_final<false, float><<<sg, 256, 0, stream>>>(gh, hst, out);
}